// Round 4
// baseline (465.970 us; speedup 1.0000x reference)
//
#include <hip/hip_runtime.h>
#include <hip/hip_bf16.h>

using bf16 = __hip_bfloat16;

#define B_      32
#define HH      56
#define WW      56
#define HIDDEN  96
#define HEADS   3
#define HD      32
#define WS_     7
#define DISP    3
#define NWH     8
#define NWW     8
#define NW      64
#define WS2     49
#define TOKENS  (B_*HH*WW)                        /* 100352 */
#define QKV_ELEMS ((size_t)B_*HEADS*NW*WS2*HD)    /* 9,633,792 */

template <typename T> __device__ inline T    encT(float v);
template <> __device__ inline float encT<float>(float v) { return v; }
template <> __device__ inline bf16  encT<bf16>(float v)  { return __float2bfloat16(v); }
template <typename T> __device__ inline float decT(T v);
template <> __device__ inline float decT<float>(float v) { return v; }
template <> __device__ inline float decT<bf16>(bf16 v)   { return __bfloat162float(v); }

// ---------------- Kernel 1: shifted gather + QKV projection + windowing ----
// 64 tokens/block; each thread: 8 tokens x 9 cols (col = colg + 32j).
// j/3 selects q/k/v, j%3 selects head, d = colg -> coalesced stores.
template <typename T>
__global__ __launch_bounds__(256, 2) void qkv_win_kernel(
    const float* __restrict__ x, const float* __restrict__ w_qkv,
    const float* __restrict__ b_qkv,
    T* __restrict__ q, T* __restrict__ k, T* __restrict__ v) {
  __shared__ float xs[64][100];   // 25.6 KB, float4-aligned rows
  __shared__ float wc[32][296];   // 37.9 KB k-chunk; banks (8k+c)%32: 2-way free
  int tid = threadIdx.x;
  int t0 = blockIdx.x * 64;

  for (int idx = tid; idx < 64 * 96; idx += 256) {
    int tl = idx / 96, ch = idx % 96;
    int tok = t0 + tl;
    int b = tok / (HH * WW); int rem = tok % (HH * WW);
    int hs = rem / WW, wsp = rem % WW;
    int h = (hs + DISP) % HH, w = (wsp + DISP) % WW;   // roll(x, -3, -3)
    xs[tl][ch] = x[((size_t)(b * HH + h) * WW + w) * HIDDEN + ch];
  }

  int colg = tid & 31, tg = tid >> 5;

  size_t base8[8];
#pragma unroll
  for (int t = 0; t < 8; t++) {
    int tok = t0 + tg * 8 + t;
    int b = tok / (HH * WW); int rem = tok % (HH * WW);
    int hs = rem / WW, wsp = rem % WW;
    int wy = hs / WS_, py = hs % WS_, wx = wsp / WS_, px = wsp % WS_;
    int nw = wy * NWW + wx, pos = py * WS_ + px;
    base8[t] = (size_t)b * (HEADS * NW * WS2 * HD) + (size_t)(nw * WS2 + pos) * HD;
  }

  float acc[8][9];
#pragma unroll
  for (int j = 0; j < 9; j++) {
    float bj = b_qkv[colg + 32 * j];
#pragma unroll
    for (int t = 0; t < 8; t++) acc[t][j] = bj;
  }

  for (int kc = 0; kc < 3; kc++) {
    __syncthreads();   // xs ready (kc=0) / wc reusable (kc>0)
    for (int idx = tid; idx < 32 * 288; idx += 256) {
      int r = idx / 288, c = idx - r * 288;
      wc[r][c] = w_qkv[(kc * 32 + r) * 288 + c];     // coalesced
    }
    __syncthreads();

    int kb = kc * 32;
    for (int kk = 0; kk < 32; kk += 4) {
      float4 xv[8];
#pragma unroll
      for (int t = 0; t < 8; t++) xv[t] = *(const float4*)&xs[tg * 8 + t][kb + kk];
#pragma unroll
      for (int j = 0; j < 9; j++) {
        int c = colg + 32 * j;
        float w0 = wc[kk + 0][c], w1 = wc[kk + 1][c];
        float w2 = wc[kk + 2][c], w3 = wc[kk + 3][c];
#pragma unroll
        for (int t = 0; t < 8; t++) {
          acc[t][j] = fmaf(xv[t].x, w0, acc[t][j]);
          acc[t][j] = fmaf(xv[t].y, w1, acc[t][j]);
          acc[t][j] = fmaf(xv[t].z, w2, acc[t][j]);
          acc[t][j] = fmaf(xv[t].w, w3, acc[t][j]);
        }
      }
    }
  }

#pragma unroll
  for (int j = 0; j < 9; j++) {
    T* dst = (j < 3) ? q : ((j < 6) ? k : v);
    int head = j % 3;
    size_t hoff = (size_t)head * (NW * WS2 * HD) + colg;
#pragma unroll
    for (int t = 0; t < 8; t++)
      dst[base8[t] + hoff] = encT<T>(acc[t][j]);
  }
}

// ---------------- Kernel 2: per-window attention --------------------------
template <typename T>
__global__ __launch_bounds__(256) void attn_kernel(
    const T* __restrict__ q, const T* __restrict__ k,
    const T* __restrict__ v, const float* __restrict__ pos_emb,
    T* __restrict__ attn_out) {
  int blk = blockIdx.x;                 // b*192 + head*64 + nw
  int nw = blk % NW; int t2 = blk / NW;
  int head = t2 % HEADS; int b = t2 / HEADS;

  __shared__ float qs[52][36];    // [i][d]
  __shared__ float ksT[32][52];   // [d][j] transposed
  __shared__ float vs[52][36];    // [j][d], rows 49-51 zeroed
  __shared__ float es[52][56];    // exp(scores), cols 49-51 zeroed
  __shared__ float pel[169];
  __shared__ float inv[52];
  int tid = threadIdx.x;

  size_t base = ((size_t)(b * HEADS + head) * NW + nw) * (WS2 * HD);
  for (int i = tid; i < WS2 * HD; i += 256) {
    int r = i >> 5, d = i & 31;
    qs[r][d] = decT<T>(q[base + i]);
    ksT[d][r] = decT<T>(k[base + i]);
    vs[r][d] = decT<T>(v[base + i]);
  }
  for (int i = tid; i < 3 * 36; i += 256) vs[49 + i / 36][i % 36] = 0.f;
  for (int i = tid; i < 32 * 3; i += 256) ksT[i / 3][49 + i % 3] = 0.f;
  for (int i = tid; i < 169; i += 256) pel[i] = pos_emb[i];
  __syncthreads();

  const float scale = 0.10206207261596575f;   // 96^-0.5 (HIDDEN, per reference)
  bool masked = (nw >= NW - NWW);             // bottom row of windows only

  // ---- QK^T + bias + mask + exp: 4i x 4j register tiles, 169 threads ----
  if (tid < 169) {
    int ig = tid / 13, jg = tid % 13;
    int i0 = ig * 4, j0 = jg * 4;
    float acc[4][4] = {};
    for (int kk = 0; kk < 32; kk += 4) {
      float4 kv0 = *(const float4*)&ksT[kk + 0][j0];
      float4 kv1 = *(const float4*)&ksT[kk + 1][j0];
      float4 kv2 = *(const float4*)&ksT[kk + 2][j0];
      float4 kv3 = *(const float4*)&ksT[kk + 3][j0];
#pragma unroll
      for (int ii = 0; ii < 4; ii++) {
        float4 qv = *(const float4*)&qs[i0 + ii][kk];
        acc[ii][0] += qv.x * kv0.x + qv.y * kv1.x + qv.z * kv2.x + qv.w * kv3.x;
        acc[ii][1] += qv.x * kv0.y + qv.y * kv1.y + qv.z * kv2.y + qv.w * kv3.y;
        acc[ii][2] += qv.x * kv0.z + qv.y * kv1.z + qv.z * kv2.z + qv.w * kv3.z;
        acc[ii][3] += qv.x * kv0.w + qv.y * kv1.w + qv.z * kv2.w + qv.w * kv3.w;
      }
    }
#pragma unroll
    for (int ii = 0; ii < 4; ii++) {
      int i = i0 + ii;
      if (i >= WS2) break;
      int yi = i / WS_, xi = i % WS_;
#pragma unroll
      for (int jj = 0; jj < 4; jj++) {
        int j = j0 + jj;
        bool dead = (j >= WS2) || (masked && ((i >= 28) != (j >= 28)));
        float e = 0.f;
        if (!dead) {
          int yj = j / WS_, xj = j % WS_;
          e = __expf(acc[ii][jj] * scale + pel[(yj - yi + 6) * 13 + (xj - xi + 6)]);
        }
        es[i][j] = e;
      }
    }
  }
  __syncthreads();

  // ---- row sums: 4 lanes per row + shfl combine ----
  if (tid < 196) {
    int i = tid >> 2, qq = tid & 3;
    float s = 0.f;
#pragma unroll
    for (int jj = 0; jj < 13; jj++) s += es[i][qq + 4 * jj];
    s += __shfl_xor(s, 1);
    s += __shfl_xor(s, 2);
    if (qq == 0) inv[i] = 1.0f / s;
  }
  __syncthreads();

  // ---- P*V: 2i x 4d register tiles, 200 threads ----
  int wy = nw / NWW, wx = nw % NWW;
  if (tid < 200) {
    int ig = tid >> 3, dg = tid & 7;
    int i0 = ig * 2, d4 = dg * 4;
    float a[2][4] = {};
    for (int j = 0; j < 52; j += 4) {
      float4 e0 = *(const float4*)&es[i0][j];
      float4 e1 = *(const float4*)&es[i0 + 1][j];
#pragma unroll
      for (int jj = 0; jj < 4; jj++) {
        float4 vv = *(const float4*)&vs[j + jj][d4];
        float ee0 = ((const float*)&e0)[jj];
        float ee1 = ((const float*)&e1)[jj];
        a[0][0] = fmaf(ee0, vv.x, a[0][0]); a[0][1] = fmaf(ee0, vv.y, a[0][1]);
        a[0][2] = fmaf(ee0, vv.z, a[0][2]); a[0][3] = fmaf(ee0, vv.w, a[0][3]);
        a[1][0] = fmaf(ee1, vv.x, a[1][0]); a[1][1] = fmaf(ee1, vv.y, a[1][1]);
        a[1][2] = fmaf(ee1, vv.z, a[1][2]); a[1][3] = fmaf(ee1, vv.w, a[1][3]);
      }
    }
#pragma unroll
    for (int ii = 0; ii < 2; ii++) {
      int i = i0 + ii;
      if (i >= WS2) continue;
      float iv = inv[i];
      int py = i / WS_, px = i % WS_;
      int hsp = wy * WS_ + py, wsp = wx * WS_ + px;
      size_t o = ((size_t)(b * HH + hsp) * WW + wsp) * HIDDEN + head * HD + d4;
      attn_out[o + 0] = encT<T>(a[ii][0] * iv);
      attn_out[o + 1] = encT<T>(a[ii][1] * iv);
      attn_out[o + 2] = encT<T>(a[ii][2] * iv);
      attn_out[o + 3] = encT<T>(a[ii][3] * iv);
    }
  }
}

// ---------------- Kernel 3: un-shift gather + output projection -----------
template <typename T>
__global__ __launch_bounds__(256, 2) void proj_kernel(
    const T* __restrict__ attn, const float* __restrict__ w_out,
    const float* __restrict__ b_out, float* __restrict__ out) {
  __shared__ float xs[64][100];
  __shared__ float wc[96][100];   // full weight resident
  int tid = threadIdx.x;
  int t0 = blockIdx.x * 64;

  for (int idx = tid; idx < 64 * 96; idx += 256) {
    int tl = idx / 96, ch = idx % 96;
    int tok = t0 + tl;
    int b = tok / (HH * WW); int rem = tok % (HH * WW);
    int h = rem / WW, w = rem % WW;
    int hs = (h - DISP + HH) % HH, wsp = (w - DISP + WW) % WW;  // roll(out,+3,+3)
    xs[tl][ch] = decT<T>(attn[((size_t)(b * HH + hs) * WW + wsp) * HIDDEN + ch]);
  }
  for (int idx = tid; idx < 96 * 96; idx += 256) {
    int r = idx / 96, c = idx - r * 96;
    wc[r][c] = w_out[idx];
  }
  __syncthreads();

  int colg = tid & 31, tg = tid >> 5;
  float acc[8][3];
#pragma unroll
  for (int j = 0; j < 3; j++) {
    float bj = b_out[colg + 32 * j];
#pragma unroll
    for (int t = 0; t < 8; t++) acc[t][j] = bj;
  }

  for (int kk = 0; kk < 96; kk += 4) {
    float4 xv[8];
#pragma unroll
    for (int t = 0; t < 8; t++) xv[t] = *(const float4*)&xs[tg * 8 + t][kk];
#pragma unroll
    for (int j = 0; j < 3; j++) {
      int c = colg + 32 * j;
      float w0 = wc[kk + 0][c], w1 = wc[kk + 1][c];
      float w2 = wc[kk + 2][c], w3 = wc[kk + 3][c];
#pragma unroll
      for (int t = 0; t < 8; t++) {
        acc[t][j] = fmaf(xv[t].x, w0, acc[t][j]);
        acc[t][j] = fmaf(xv[t].y, w1, acc[t][j]);
        acc[t][j] = fmaf(xv[t].z, w2, acc[t][j]);
        acc[t][j] = fmaf(xv[t].w, w3, acc[t][j]);
      }
    }
  }

#pragma unroll
  for (int j = 0; j < 3; j++)
#pragma unroll
    for (int t = 0; t < 8; t++)
      out[(size_t)(t0 + tg * 8 + t) * HIDDEN + colg + 32 * j] = acc[t][j];
}

extern "C" void kernel_launch(void* const* d_in, const int* in_sizes, int n_in,
                              void* d_out, int out_size, void* d_ws, size_t ws_size,
                              hipStream_t stream) {
  const float* x     = (const float*)d_in[0];
  const float* w_qkv = (const float*)d_in[1];
  const float* b_qkv = (const float*)d_in[2];
  const float* pos   = (const float*)d_in[3];
  const float* w_out = (const float*)d_in[4];
  const float* b_out = (const float*)d_in[5];
  float* out = (float*)d_out;

  // bf16 workspace: halves HBM traffic for q/k/v/attn, error well within budget
  bf16* qb = (bf16*)d_ws;
  bf16* kb = qb + QKV_ELEMS;
  bf16* vb = kb + QKV_ELEMS;
  bf16* ab = vb + QKV_ELEMS;
  qkv_win_kernel<bf16><<<TOKENS / 64, 256, 0, stream>>>(x, w_qkv, b_qkv, qb, kb, vb);
  attn_kernel<bf16><<<B_ * HEADS * NW, 256, 0, stream>>>(qb, kb, vb, pos, ab);
  proj_kernel<bf16><<<TOKENS / 64, 256, 0, stream>>>(ab, w_out, b_out, out);
}